// Round 1
// baseline (543.688 us; speedup 1.0000x reference)
//
#include <hip/hip_runtime.h>
#include <hip/hip_bf16.h>

// GAT layer: xt = x@W; alpha = segment_softmax(leakyrelu(asrc[src]+adst[dst])); 
// out = relu(mean_h(segment_sum(alpha*xt[src])) + bias)
// N=50000, F_IN=116, H=8, C=32, E=800000 (+N self loops)

#define F_IN 116
#define HC 256     // H*C
#define NHEAD 8
#define CDIM 32

// ---------------- zero scratch counters ----------------
__global__ void zero_k(int* __restrict__ p, int n) {
    int i = blockIdx.x * 256 + threadIdx.x;
    if (i < n) p[i] = 0;
}

// ---------------- GEMM: xt[N,256] = x[N,116] @ W[116,256] ----------------
// block = 256 threads (4 waves). Block covers 64 rows; wave w handles rows [w*16, w*16+16).
// Each thread handles 4 columns: lane, lane+64, lane+128, lane+192.
__global__ __launch_bounds__(256) void gemm_xt(const float* __restrict__ x,
                                               const float* __restrict__ W,
                                               float* __restrict__ xt, int N) {
    __shared__ float xs[64 * F_IN];           // 29696 B
    const int t = threadIdx.x;
    const int row0 = blockIdx.x * 64;
    const int nrows = (N - row0 < 64) ? (N - row0) : 64;
    const int tot = nrows * F_IN;
    for (int i = t; i < tot; i += 256) xs[i] = x[(size_t)row0 * F_IN + i];
    __syncthreads();

    const int w = t >> 6;
    const int lane = t & 63;
    const int r0 = w * 16;

    float acc[16][4];
#pragma unroll
    for (int r = 0; r < 16; ++r)
#pragma unroll
        for (int j = 0; j < 4; ++j) acc[r][j] = 0.f;

    for (int k4 = 0; k4 < F_IN / 4; ++k4) {
        const int k = k4 * 4;
        float w0[4], w1[4], w2[4], w3[4];
#pragma unroll
        for (int j = 0; j < 4; ++j) {
            const float* Wk = W + k * HC + lane + 64 * j;
            w0[j] = Wk[0];
            w1[j] = Wk[HC];
            w2[j] = Wk[2 * HC];
            w3[j] = Wk[3 * HC];
        }
#pragma unroll
        for (int r = 0; r < 16; ++r) {
            float4 xv = *(const float4*)&xs[(r0 + r) * F_IN + k];
#pragma unroll
            for (int j = 0; j < 4; ++j)
                acc[r][j] = fmaf(xv.x, w0[j],
                            fmaf(xv.y, w1[j],
                            fmaf(xv.z, w2[j],
                            fmaf(xv.w, w3[j], acc[r][j]))));
        }
    }

#pragma unroll
    for (int r = 0; r < 16; ++r) {
        const int row = row0 + r0 + r;
        if (row < N) {
#pragma unroll
            for (int j = 0; j < 4; ++j)
                xt[(size_t)row * HC + lane + 64 * j] = acc[r][j];
        }
    }
}

// ---------------- alphas: per (n,h) dot of xt row-slice with att vectors ----------------
__global__ void alphas_k(const float* __restrict__ xt,
                         const float* __restrict__ att_s,
                         const float* __restrict__ att_d,
                         float* __restrict__ asrc, float* __restrict__ adst, int NH) {
    int idx = blockIdx.x * 256 + threadIdx.x;    // n*8 + h
    if (idx >= NH) return;
    int h = idx & 7;
    int n = idx >> 3;
    const float4* xp = (const float4*)(xt + (size_t)n * HC + h * CDIM);
    const float4* sp = (const float4*)(att_s + h * CDIM);
    const float4* dp = (const float4*)(att_d + h * CDIM);
    float a = 0.f, b = 0.f;
#pragma unroll
    for (int q = 0; q < CDIM / 4; ++q) {
        float4 v = xp[q], sv = sp[q], dv = dp[q];
        a += v.x * sv.x + v.y * sv.y + v.z * sv.z + v.w * sv.w;
        b += v.x * dv.x + v.y * dv.y + v.z * dv.z + v.w * dv.w;
    }
    asrc[idx] = a;
    adst[idx] = b;
}

// ---------------- in-degree histogram ----------------
__global__ void hist_k(const int* __restrict__ dst, int* __restrict__ cnt, int E) {
    int e = blockIdx.x * 256 + threadIdx.x;
    if (e < E) atomicAdd(&cnt[dst[e]], 1);
}

// ---------------- single-block exclusive scan: offs[0..N] ----------------
#define SCAN_T 1024
__global__ __launch_bounds__(SCAN_T) void scan_k(const int* __restrict__ cnt,
                                                 int* __restrict__ offs, int N) {
    __shared__ int sums[SCAN_T];
    const int t = threadIdx.x;
    const int chunk = (N + SCAN_T - 1) / SCAN_T;
    const int b = t * chunk;
    const int e = (b + chunk < N) ? (b + chunk) : N;
    int s = 0;
    for (int i = b; i < e; ++i) s += cnt[i];
    sums[t] = s;
    __syncthreads();
    for (int off = 1; off < SCAN_T; off <<= 1) {
        int v = (t >= off) ? sums[t - off] : 0;
        __syncthreads();
        sums[t] += v;
        __syncthreads();
    }
    int run = (t == 0) ? 0 : sums[t - 1];
    for (int i = b; i < e; ++i) { offs[i] = run; run += cnt[i]; }
    if (t == SCAN_T - 1) offs[N] = sums[SCAN_T - 1];
}

// ---------------- CSR scatter ----------------
__global__ void scatter_k(const int* __restrict__ src, const int* __restrict__ dst,
                          const int* __restrict__ offs, int* __restrict__ cur,
                          int* __restrict__ csr, int E) {
    int e = blockIdx.x * 256 + threadIdx.x;
    if (e >= E) return;
    int d = dst[e];
    int p = offs[d] + atomicAdd(&cur[d], 1);
    csr[p] = src[e];
}

// ---------------- aggregate: one block per destination node ----------------
// 256 threads: t = h*32 + c. Self loop handled as virtual edge index d.
__global__ __launch_bounds__(256) void aggregate_k(const float* __restrict__ xt,
                                                   const float* __restrict__ asrc,
                                                   const float* __restrict__ adst,
                                                   const int* __restrict__ offs,
                                                   const int* __restrict__ csr,
                                                   const float* __restrict__ bias,
                                                   float* __restrict__ out, int N) {
    const int n = blockIdx.x;
    const int t = threadIdx.x;
    const int h = t >> 5;
    const int c = t & 31;
    const int beg = offs[n];
    const int d = offs[n + 1] - beg;
    const float adst_h = adst[n * NHEAD + h];

    // phase A1: max logit over edges (incl. self loop at i==d), per head
    float lmax = -1e30f;
    for (int i = c; i <= d; i += 32) {
        int s = (i < d) ? csr[beg + i] : n;
        float z = asrc[s * NHEAD + h] + adst_h;
        z = (z > 0.f) ? z : 0.2f * z;
        lmax = fmaxf(lmax, z);
    }
#pragma unroll
    for (int o = 16; o; o >>= 1) lmax = fmaxf(lmax, __shfl_xor(lmax, o, 32));

    // phase A2: sum of exp
    float lsum = 0.f;
    for (int i = c; i <= d; i += 32) {
        int s = (i < d) ? csr[beg + i] : n;
        float z = asrc[s * NHEAD + h] + adst_h;
        z = (z > 0.f) ? z : 0.2f * z;
        lsum += __expf(z - lmax);
    }
#pragma unroll
    for (int o = 16; o; o >>= 1) lsum += __shfl_xor(lsum, o, 32);
    const float inv = 1.f / (lsum + 1e-16f);

    // phase B: weighted aggregation
    float acc = 0.f;
    for (int i = 0; i <= d; ++i) {
        int s = (i < d) ? csr[beg + i] : n;
        float z = asrc[s * NHEAD + h] + adst_h;
        z = (z > 0.f) ? z : 0.2f * z;
        float wgt = __expf(z - lmax) * inv;
        acc = fmaf(wgt, xt[(size_t)s * HC + t], acc);
    }

    // reduce over heads, mean + bias + relu
    __shared__ float red[256];
    red[t] = acc;
    __syncthreads();
    if (t < CDIM) {
        float v = red[t] + red[t + 32] + red[t + 64] + red[t + 96] +
                  red[t + 128] + red[t + 160] + red[t + 192] + red[t + 224];
        v = v * (1.f / NHEAD) + bias[t];
        out[n * CDIM + t] = fmaxf(v, 0.f);
    }
}

extern "C" void kernel_launch(void* const* d_in, const int* in_sizes, int n_in,
                              void* d_out, int out_size, void* d_ws, size_t ws_size,
                              hipStream_t stream) {
    const float* x     = (const float*)d_in[0];
    const int*   ei    = (const int*)d_in[1];      // [2,E] int32: row0=src, row1=dst
    const float* W     = (const float*)d_in[2];
    const float* att_s = (const float*)d_in[3];
    const float* att_d = (const float*)d_in[4];
    const float* bias  = (const float*)d_in[5];
    float* out = (float*)d_out;

    const int N = in_sizes[0] / F_IN;    // 50000
    const int E = in_sizes[1] / 2;       // 800000

    // workspace layout
    float* xt   = (float*)d_ws;                       // N*256 f32
    float* asrc = xt + (size_t)N * HC;                // N*8
    float* adst = asrc + (size_t)N * NHEAD;           // N*8
    int*   offs = (int*)(adst + (size_t)N * NHEAD);   // N+1
    int*   cnt  = offs + (N + 1);                     // N
    int*   cur  = cnt + N;                            // N
    int*   csr  = cur + N;                            // E

    zero_k<<<(2 * N + 255) / 256, 256, 0, stream>>>(cnt, 2 * N);   // cnt + cur contiguous
    gemm_xt<<<(N + 63) / 64, 256, 0, stream>>>(x, W, xt, N);
    alphas_k<<<(N * NHEAD + 255) / 256, 256, 0, stream>>>(xt, att_s, att_d, asrc, adst, N * NHEAD);
    hist_k<<<(E + 255) / 256, 256, 0, stream>>>(ei + E, cnt, E);
    scan_k<<<1, SCAN_T, 0, stream>>>(cnt, offs, N);
    scatter_k<<<(E + 255) / 256, 256, 0, stream>>>(ei, ei + E, offs, cur, csr, E);
    aggregate_k<<<N, 256, 0, stream>>>(xt, asrc, adst, offs, csr, bias, out, N);
}